// Round 8
// baseline (524.737 us; speedup 1.0000x reference)
//
#include <hip/hip_runtime.h>

// CausalSelfAttention: B=8, S=2048, D=512, fp32 in/out, Q=K=V=x, no scale.
// Round 11: r10 structure + 4 blocks/CU + cluster work map + defer-max.
//   r10 post-mortem: 103us, nothing saturated (Mfma 14.5, VALU 50, LDS ~40%,
//   L2 60%) -> latency-bound at 2 waves/SIMD; T_tile/wave ~950cy ~= serial
//   path (exchange ~400 + softmax ~300 + PV ~150 + QK ~100). Changes:
//     - __launch_bounds__(256,4): 4 blocks/CU (VGPR 80 <= 128 cap, LDS
//       21.5KBx4 = 86KB <= 160KB). 4 waves/SIMD covers the latency.
//     - cluster map rg = 4*(u&31) + (u>>5): smooth in u, so under ANY
//       locality-based dispatch (breadth round-robin OR depth-first) the 4
//       co-resident blocks per CU have tiles within +-2 -> CU stays 4-deep
//       until all its blocks finish together (equal-size-per-CU beats
//       equal-total-per-CU when per-tile wall is latency not ports).
//       bat = bid&7 keeps batch->XCD L2 affinity.
//     - T13 defer-max: rescale only when tile max exceeds running max by >8.
//       Exact math (l and p both use the same sticky m; p <= e^8 fits fp32).
//   Geometry unchanged: 1024 blocks x 256 thr (4 waves), block = one 16-row
//   group; QK split by D-quarter (K in regs, partials exchange-summed, fixed
//   order -> bit-identical S in all waves); PV split by col-quarter, V in
//   regs; K(t+1)/V(t+1) prefetched into regs behind WAR deps; ONE barrier
//   per tile (Xc parity dbuf).
// ws: [0,16MiB) Kf, [16MiB,32MiB) Vf.

#define S_LEN 2048
#define D_DIM 512
#define BATCH_ELEMS 1048576  // 2 MiB bf16 per batch per array

typedef short s16x8 __attribute__((ext_vector_type(8)));
typedef float f32x4 __attribute__((ext_vector_type(4)));

__device__ __forceinline__ unsigned short f2b_rne(float f) {
  unsigned int u = __float_as_uint(f);
  return (unsigned short)((u + 0x7FFFu + ((u >> 16) & 1u)) >> 16);
}
__device__ __forceinline__ unsigned short f2b_fast(float f) {
  return (unsigned short)((__float_as_uint(f) + 0x8000u) >> 16);
}

template <int CTRL>
__device__ __forceinline__ float dppf(float x) {
  return __uint_as_float((unsigned)__builtin_amdgcn_update_dpp(
      0, (int)__float_as_uint(x), CTRL, 0xF, 0xF, true));
}
__device__ __forceinline__ float red16_max(float v) {
  v = fmaxf(v, dppf<0xB1>(v));   // xor 1
  v = fmaxf(v, dppf<0x4E>(v));   // xor 2
  v = fmaxf(v, dppf<0x124>(v));  // row_ror:4
  v = fmaxf(v, dppf<0x128>(v));  // row_ror:8
  return v;
}
__device__ __forceinline__ float red16_sum(float v) {
  v += dppf<0xB1>(v);
  v += dppf<0x4E>(v);
  v += dppf<0x124>(v);
  v += dppf<0x128>(v);
  return v;
}

// ---------------------------------------------------------------------------
// Prepass: pack x into Kf and Vf fragment order. 2048 blocks x 256 thr,
// 64x64 tile per block. A = [s][d] bf16, T = [d][s] bf16 (stride 72, 16B-al).
//   Kf[b][kg:128][db:16][lane:64][8]  elem = x[b][16*kg+l15][32*db+8*quad+j]
//   Vf[b][dg:32][kb:64][lane:64][8]   elem = x[b][32*kb+8*quad+j][16*dg+l15]
// ---------------------------------------------------------------------------
__global__ void pack_kernel(const float* __restrict__ x,
                            unsigned short* __restrict__ Kf,
                            unsigned short* __restrict__ Vf) {
  __shared__ unsigned short A[64 * 72];
  __shared__ unsigned short T[64 * 72];
  const int bid = blockIdx.x;
  const int b = bid >> 8, rem = bid & 255;
  const int s0 = (rem >> 3) * 64, d0 = (rem & 7) * 64;
  const int tid = threadIdx.x;

  // pass 1: load + convert, fill A[s][d]
  #pragma unroll
  for (int it = 0; it < 2; ++it) {
    int slot = it * 256 + tid;          // 0..511
    int row = slot >> 3, c = slot & 7;  // row 0..63, 8-col group
    const float* src = x + ((size_t)(b * S_LEN + s0 + row)) * D_DIM + d0 + c * 8;
    const float4 v0 = *(const float4*)(src);
    const float4 v1 = *(const float4*)(src + 4);
    s16x8 o;
    o[0] = (short)f2b_rne(v0.x); o[1] = (short)f2b_rne(v0.y);
    o[2] = (short)f2b_rne(v0.z); o[3] = (short)f2b_rne(v0.w);
    o[4] = (short)f2b_rne(v1.x); o[5] = (short)f2b_rne(v1.y);
    o[6] = (short)f2b_rne(v1.z); o[7] = (short)f2b_rne(v1.w);
    *(s16x8*)&A[row * 72 + c * 8] = o;
  }
  __syncthreads();

  // pass 2: transpose A -> T in 4x4 micro-blocks (vector b64 ops)
  {
    int sr = tid >> 4, sc = tid & 15;
    ushort4 a0 = *(const ushort4*)&A[(4 * sr + 0) * 72 + 4 * sc];
    ushort4 a1 = *(const ushort4*)&A[(4 * sr + 1) * 72 + 4 * sc];
    ushort4 a2 = *(const ushort4*)&A[(4 * sr + 2) * 72 + 4 * sc];
    ushort4 a3 = *(const ushort4*)&A[(4 * sr + 3) * 72 + 4 * sc];
    ushort4 t0; t0.x = a0.x; t0.y = a1.x; t0.z = a2.x; t0.w = a3.x;
    ushort4 t1; t1.x = a0.y; t1.y = a1.y; t1.z = a2.y; t1.w = a3.y;
    ushort4 t2; t2.x = a0.z; t2.y = a1.z; t2.z = a2.z; t2.w = a3.z;
    ushort4 t3; t3.x = a0.w; t3.y = a1.w; t3.z = a2.w; t3.w = a3.w;
    *(ushort4*)&T[(4 * sc + 0) * 72 + 4 * sr] = t0;
    *(ushort4*)&T[(4 * sc + 1) * 72 + 4 * sr] = t1;
    *(ushort4*)&T[(4 * sc + 2) * 72 + 4 * sr] = t2;
    *(ushort4*)&T[(4 * sc + 3) * 72 + 4 * sr] = t3;
  }
  __syncthreads();

  // pass 3: emit fragment blocks (each 64 consecutive threads write 1KB)
  #pragma unroll
  for (int it = 0; it < 2; ++it) {
    int slot = it * 256 + tid;
    int frag = slot >> 6;               // 0..7
    int lane = slot & 63;
    int l15 = lane & 15, quad = lane >> 4;
    int f1 = frag >> 1, f0 = frag & 1;  // f1: 0..3, f0: 0..1
    // Kf: kgl=f1 (16 rows), dbl=f0 (32 cols)
    {
      s16x8 val = *(const s16x8*)&A[(f1 * 16 + l15) * 72 + f0 * 32 + quad * 8];
      size_t kg = (size_t)(s0 >> 4) + f1, db = (size_t)(d0 >> 5) + f0;
      *(s16x8*)(Kf + (size_t)b * BATCH_ELEMS + (kg * 16 + db) * 512 + lane * 8) = val;
    }
    // Vf: dgl=f1 (16 cols), kbl=f0 (32 rows)
    {
      s16x8 val = *(const s16x8*)&T[(f1 * 16 + l15) * 72 + f0 * 32 + quad * 8];
      size_t dg = (size_t)(d0 >> 4) + f1, kb = (size_t)(s0 >> 5) + f0;
      *(s16x8*)(Vf + (size_t)b * BATCH_ELEMS + (dg * 64 + kb) * 512 + lane * 8) = val;
    }
  }
}

// ---------------------------------------------------------------------------
// Flash attention: 16-row blocks, 4 waves quarter D (QK^T from K-in-regs,
// exchange-summed) and quarter cols (PV, V in regs). LDS: exchange + P only.
// MFMA 16x16x32 layouts: A[m=l15][k=quad*8+j], B[k=quad*8+j][n=l15],
// C/D: col=l15, row=quad*4+reg.
// ---------------------------------------------------------------------------
__global__ __launch_bounds__(256, 4)
void attn_kernel(const unsigned short* __restrict__ Kf,
                 const unsigned short* __restrict__ Vf,
                 float* __restrict__ out) {
  __shared__ float Xc[2][4][512];         // parity-dbuf per-wave partial S
  __shared__ unsigned short Pw[4][16 * 40];

  const int bid = blockIdx.x;
  const int bat = bid & 7;                // batch == XCD under round-robin
  const int u = bid >> 3;                 // 0..127
  const int rg = ((u & 31) << 2) | (u >> 5);  // cluster map: co-resident
                                              // blocks have ~equal tiles
  const int q0 = rg * 16;
  const int tmax = rg >> 1;               // tiles: tmax+1
  const int tid = threadIdx.x;
  const int w = tid >> 6;                 // 0..3: D-quarter / col-quarter
  const int lane = tid & 63;
  const int l15 = lane & 15, quad = lane >> 4;
  const size_t batOff = (size_t)bat * BATCH_ELEMS;

  // K fragments for this wave's D-quarter (db = w*4..w*4+3, both key halves)
  s16x8 kreg[8];
  auto loadK = [&](int kt) {
    const unsigned short* kb = Kf + batOff + (size_t)kt * 16384 + lane * 8;
    #pragma unroll
    for (int i = 0; i < 4; ++i) {
      kreg[i]     = *(const s16x8*)(kb + (size_t)(w * 4 + i) * 512);        // keys 0-15
      kreg[4 + i] = *(const s16x8*)(kb + (size_t)(16 + w * 4 + i) * 512);   // keys 16-31
    }
  };

  // V fragments for this wave's col-quarter (cols w*128..+127), in registers
  s16x8 vreg[8];
  auto loadV = [&](int kt) {
    const unsigned short* vb = Vf + batOff + (size_t)kt * 512 + lane * 8;
    #pragma unroll
    for (int dgl = 0; dgl < 8; ++dgl)
      vreg[dgl] = *(const s16x8*)(vb + (size_t)(w * 8 + dgl) * 32768);
  };

  // prologue: K(0), V(0), Q fragments (latency exposed once)
  loadK(0);
  loadV(0);

  // Q fragments: rows q0..q0+15, D-quarter w (db = w*4 + i)
  s16x8 qf[4];
  {
    const unsigned short* qb =
        Kf + batOff + ((size_t)rg * 16 + w * 4) * 512 + lane * 8;
    #pragma unroll
    for (int i = 0; i < 4; ++i) qf[i] = *(const s16x8*)(qb + i * 512);
  }

  f32x4 O[8];
  float m[4], l[4];
  #pragma unroll
  for (int n = 0; n < 8; ++n) O[n] = (f32x4){0.f, 0.f, 0.f, 0.f};
  #pragma unroll
  for (int r = 0; r < 4; ++r) { m[r] = -3e38f; l[r] = 0.f; }

  for (int kt = 0;; ++kt) {
    const int p = kt & 1;

    // ---- QK^T partial over this wave's D-quarter (K from regs) ----
    f32x4 sacc[2];
    sacc[0] = (f32x4){0.f, 0.f, 0.f, 0.f};
    sacc[1] = (f32x4){0.f, 0.f, 0.f, 0.f};
    __builtin_amdgcn_s_setprio(1);
    #pragma unroll
    for (int i = 0; i < 4; ++i) {
      sacc[0] = __builtin_amdgcn_mfma_f32_16x16x32_bf16(qf[i], kreg[i], sacc[0], 0, 0, 0);
      sacc[1] = __builtin_amdgcn_mfma_f32_16x16x32_bf16(qf[i], kreg[4 + i], sacc[1], 0, 0, 0);
    }
    __builtin_amdgcn_s_setprio(0);

    // ---- prefetch K(t+1) into kreg (WAR pins after QK); lands during
    //      exchange+softmax+PV, consumed next tile (~1200cy later) ----
    if (kt < tmax) loadK(kt + 1);

    // ---- 4-way exchange: publish partial, ONE barrier, fixed-order sum ----
    *(f32x4*)&Xc[p][w][lane * 4] = sacc[0];
    *(f32x4*)&Xc[p][w][256 + lane * 4] = sacc[1];
    asm volatile("s_waitcnt lgkmcnt(0)" ::: "memory");
    __builtin_amdgcn_s_barrier();
    __builtin_amdgcn_sched_barrier(0);
    {
      f32x4 s0 = *(const f32x4*)&Xc[p][0][lane * 4];
      s0 += *(const f32x4*)&Xc[p][1][lane * 4];
      s0 += *(const f32x4*)&Xc[p][2][lane * 4];
      s0 += *(const f32x4*)&Xc[p][3][lane * 4];
      f32x4 s1 = *(const f32x4*)&Xc[p][0][256 + lane * 4];
      s1 += *(const f32x4*)&Xc[p][1][256 + lane * 4];
      s1 += *(const f32x4*)&Xc[p][2][256 + lane * 4];
      s1 += *(const f32x4*)&Xc[p][3][256 + lane * 4];
      sacc[0] = s0;
      sacc[1] = s1;
    }

    if (kt == tmax) {  // causal mask on diagonal tile
      #pragma unroll
      for (int kg2 = 0; kg2 < 2; ++kg2)
        #pragma unroll
        for (int r = 0; r < 4; ++r) {
          int key = kt * 32 + kg2 * 16 + l15;
          int row = q0 + quad * 4 + r;
          if (key > row) sacc[kg2][r] = -3e38f;
        }
    }

    // ---- online softmax (registers + DPP; identical in all 4 waves) ----
    // T13 defer-max: keep sticky m unless tile max exceeds it by >8.
    // Exact: l and p use the same m; p <= e^8 fits fp32/bf16 comfortably.
    float mt[4], alpha[4];
    #pragma unroll
    for (int r = 0; r < 4; ++r)
      mt[r] = red16_max(fmaxf(sacc[0][r], sacc[1][r]));
    bool needAny = (mt[0] > m[0] + 8.f) | (mt[1] > m[1] + 8.f) |
                   (mt[2] > m[2] + 8.f) | (mt[3] > m[3] + 8.f);
    unsigned long long bal = __ballot(needAny);
    if (bal) {
      #pragma unroll
      for (int r = 0; r < 4; ++r) {
        float mn = fmaxf(m[r], mt[r]);
        alpha[r] = __expf(m[r] - mn);
        m[r] = mn;
      }
    } else {
      #pragma unroll
      for (int r = 0; r < 4; ++r) alpha[r] = 1.0f;
    }
    float p2[2][4];
    #pragma unroll
    for (int kg2 = 0; kg2 < 2; ++kg2)
      #pragma unroll
      for (int r = 0; r < 4; ++r) p2[kg2][r] = __expf(sacc[kg2][r] - m[r]);
    #pragma unroll
    for (int r = 0; r < 4; ++r)
      l[r] = l[r] * alpha[r] + red16_sum(p2[0][r] + p2[1][r]);

    // ---- P: C-layout -> A-layout via wave-private LDS ----
    #pragma unroll
    for (int kg2 = 0; kg2 < 2; ++kg2)
      #pragma unroll
      for (int r = 0; r < 4; ++r)
        Pw[w][(quad * 4 + r) * 40 + kg2 * 16 + l15] = f2b_fast(p2[kg2][r]);
    s16x8 pa = *(const s16x8*)&Pw[w][l15 * 40 + quad * 8];

    if (bal) {
      #pragma unroll
      for (int n = 0; n < 8; ++n)
        #pragma unroll
        for (int r = 0; r < 4; ++r) O[n][r] *= alpha[r];
    }

    // ---- PV: O[16 rows][cols w*128..+127] += P(16x32) * V-quarter (regs) ----
    __builtin_amdgcn_s_setprio(1);
    #pragma unroll
    for (int dgl = 0; dgl < 8; ++dgl)
      O[dgl] = __builtin_amdgcn_mfma_f32_16x16x32_bf16(pa, vreg[dgl], O[dgl], 0, 0, 0);
    __builtin_amdgcn_s_setprio(0);

    if (kt == tmax) break;

    // ---- prefetch V(t+1) (WAR pins after PV); no loop-end barrier needed:
    //      Xc parity gives 2-tile reuse distance, barrier(t+1) orders it ----
    loadV(kt + 1);
  }

  // ---- epilogue: wave writes its 16 rows x 128-col quarter ----
  float invl[4];
  #pragma unroll
  for (int r = 0; r < 4; ++r) invl[r] = 1.0f / l[r];
  float* ob = out + ((size_t)(bat * S_LEN + q0)) * D_DIM + w * 128;
  #pragma unroll
  for (int dgl = 0; dgl < 8; ++dgl)
    #pragma unroll
    for (int r = 0; r < 4; ++r)
      ob[(size_t)(quad * 4 + r) * D_DIM + dgl * 16 + l15] = O[dgl][r] * invl[r];
}

extern "C" void kernel_launch(void* const* d_in, const int* in_sizes, int n_in,
                              void* d_out, int out_size, void* d_ws, size_t ws_size,
                              hipStream_t stream) {
  (void)in_sizes; (void)n_in; (void)out_size; (void)ws_size;
  const float* x = (const float*)d_in[0];
  float* out = (float*)d_out;
  unsigned short* Kf = (unsigned short*)d_ws;                         // 16 MiB
  unsigned short* Vf = (unsigned short*)((char*)d_ws + (16u << 20));  // 16 MiB
  pack_kernel<<<2048, 256, 0, stream>>>(x, Kf, Vf);
  attn_kernel<<<1024, 256, 0, stream>>>(Kf, Vf, out);
}

// Round 9
// 173.469 us; speedup vs baseline: 3.0250x; 3.0250x over previous
//
#include <hip/hip_runtime.h>

// CausalSelfAttention: B=8, S=2048, D=512, fp32 in/out, Q=K=V=x, no scale.
// Round 12: r10 (103us) + 3 blocks/CU + defer-max + 6-read exchange.
//   r11 post-mortem: __launch_bounds__(256,4) capped unified VGPR+AGPR at
//   512/4=128 < the kernel's ~150 demand -> 430MB/dispatch scratch traffic
//   (WRITE 440MB), 465us. The occupancy theory was right, the ask was wrong:
//   3 waves/SIMD caps regs at ~168 >= 150 -> fits without spill.
//     - __launch_bounds__(256,3): 3 blocks/CU (LDS 21.5KBx3=64.5KB OK).
//       Latency-bound kernel -> ~1.4x throughput from 2->3 waves/SIMD.
//     - T13 defer-max (thr=8, validated by r11's passing run): skip O-rescale
//       and m-update unless tile max exceeds sticky m by >8. Exact: l and p
//       use the same sticky m; p <= e^8 fits fp32/bf16 fine.
//     - 6-read exchange: use own sacc regs in slot w (same value, same fixed
//       add order -> bit-identical S across waves); 6 ds_read_b128 not 8.
//     - work map back to r10's rg = 127-u: smooth (co-resident blocks within
//       +-3 tiles) AND LPT (heaviest first). bat=bid&7 -> batch==XCD L2.
//   Geometry: 1024 blocks x 256 thr (4 waves), block = one 16-row group;
//   QK split by D-quarter (K in regs, partials exchange-summed); PV split by
//   col-quarter, V in regs; K(t+1)/V(t+1) prefetched behind WAR deps; ONE
//   barrier per tile (Xc parity dbuf).
// ws: [0,16MiB) Kf, [16MiB,32MiB) Vf.

#define S_LEN 2048
#define D_DIM 512
#define BATCH_ELEMS 1048576  // 2 MiB bf16 per batch per array

typedef short s16x8 __attribute__((ext_vector_type(8)));
typedef float f32x4 __attribute__((ext_vector_type(4)));

__device__ __forceinline__ unsigned short f2b_rne(float f) {
  unsigned int u = __float_as_uint(f);
  return (unsigned short)((u + 0x7FFFu + ((u >> 16) & 1u)) >> 16);
}
__device__ __forceinline__ unsigned short f2b_fast(float f) {
  return (unsigned short)((__float_as_uint(f) + 0x8000u) >> 16);
}

template <int CTRL>
__device__ __forceinline__ float dppf(float x) {
  return __uint_as_float((unsigned)__builtin_amdgcn_update_dpp(
      0, (int)__float_as_uint(x), CTRL, 0xF, 0xF, true));
}
__device__ __forceinline__ float red16_max(float v) {
  v = fmaxf(v, dppf<0xB1>(v));   // xor 1
  v = fmaxf(v, dppf<0x4E>(v));   // xor 2
  v = fmaxf(v, dppf<0x124>(v));  // row_ror:4
  v = fmaxf(v, dppf<0x128>(v));  // row_ror:8
  return v;
}
__device__ __forceinline__ float red16_sum(float v) {
  v += dppf<0xB1>(v);
  v += dppf<0x4E>(v);
  v += dppf<0x124>(v);
  v += dppf<0x128>(v);
  return v;
}

// ---------------------------------------------------------------------------
// Prepass: pack x into Kf and Vf fragment order. 2048 blocks x 256 thr,
// 64x64 tile per block. A = [s][d] bf16, T = [d][s] bf16 (stride 72, 16B-al).
//   Kf[b][kg:128][db:16][lane:64][8]  elem = x[b][16*kg+l15][32*db+8*quad+j]
//   Vf[b][dg:32][kb:64][lane:64][8]   elem = x[b][32*kb+8*quad+j][16*dg+l15]
// ---------------------------------------------------------------------------
__global__ void pack_kernel(const float* __restrict__ x,
                            unsigned short* __restrict__ Kf,
                            unsigned short* __restrict__ Vf) {
  __shared__ unsigned short A[64 * 72];
  __shared__ unsigned short T[64 * 72];
  const int bid = blockIdx.x;
  const int b = bid >> 8, rem = bid & 255;
  const int s0 = (rem >> 3) * 64, d0 = (rem & 7) * 64;
  const int tid = threadIdx.x;

  // pass 1: load + convert, fill A[s][d]
  #pragma unroll
  for (int it = 0; it < 2; ++it) {
    int slot = it * 256 + tid;          // 0..511
    int row = slot >> 3, c = slot & 7;  // row 0..63, 8-col group
    const float* src = x + ((size_t)(b * S_LEN + s0 + row)) * D_DIM + d0 + c * 8;
    const float4 v0 = *(const float4*)(src);
    const float4 v1 = *(const float4*)(src + 4);
    s16x8 o;
    o[0] = (short)f2b_rne(v0.x); o[1] = (short)f2b_rne(v0.y);
    o[2] = (short)f2b_rne(v0.z); o[3] = (short)f2b_rne(v0.w);
    o[4] = (short)f2b_rne(v1.x); o[5] = (short)f2b_rne(v1.y);
    o[6] = (short)f2b_rne(v1.z); o[7] = (short)f2b_rne(v1.w);
    *(s16x8*)&A[row * 72 + c * 8] = o;
  }
  __syncthreads();

  // pass 2: transpose A -> T in 4x4 micro-blocks (vector b64 ops)
  {
    int sr = tid >> 4, sc = tid & 15;
    ushort4 a0 = *(const ushort4*)&A[(4 * sr + 0) * 72 + 4 * sc];
    ushort4 a1 = *(const ushort4*)&A[(4 * sr + 1) * 72 + 4 * sc];
    ushort4 a2 = *(const ushort4*)&A[(4 * sr + 2) * 72 + 4 * sc];
    ushort4 a3 = *(const ushort4*)&A[(4 * sr + 3) * 72 + 4 * sc];
    ushort4 t0; t0.x = a0.x; t0.y = a1.x; t0.z = a2.x; t0.w = a3.x;
    ushort4 t1; t1.x = a0.y; t1.y = a1.y; t1.z = a2.y; t1.w = a3.y;
    ushort4 t2; t2.x = a0.z; t2.y = a1.z; t2.z = a2.z; t2.w = a3.z;
    ushort4 t3; t3.x = a0.w; t3.y = a1.w; t3.z = a2.w; t3.w = a3.w;
    *(ushort4*)&T[(4 * sc + 0) * 72 + 4 * sr] = t0;
    *(ushort4*)&T[(4 * sc + 1) * 72 + 4 * sr] = t1;
    *(ushort4*)&T[(4 * sc + 2) * 72 + 4 * sr] = t2;
    *(ushort4*)&T[(4 * sc + 3) * 72 + 4 * sr] = t3;
  }
  __syncthreads();

  // pass 3: emit fragment blocks (each 64 consecutive threads write 1KB)
  #pragma unroll
  for (int it = 0; it < 2; ++it) {
    int slot = it * 256 + tid;
    int frag = slot >> 6;               // 0..7
    int lane = slot & 63;
    int l15 = lane & 15, quad = lane >> 4;
    int f1 = frag >> 1, f0 = frag & 1;  // f1: 0..3, f0: 0..1
    // Kf: kgl=f1 (16 rows), dbl=f0 (32 cols)
    {
      s16x8 val = *(const s16x8*)&A[(f1 * 16 + l15) * 72 + f0 * 32 + quad * 8];
      size_t kg = (size_t)(s0 >> 4) + f1, db = (size_t)(d0 >> 5) + f0;
      *(s16x8*)(Kf + (size_t)b * BATCH_ELEMS + (kg * 16 + db) * 512 + lane * 8) = val;
    }
    // Vf: dgl=f1 (16 cols), kbl=f0 (32 rows)
    {
      s16x8 val = *(const s16x8*)&T[(f1 * 16 + l15) * 72 + f0 * 32 + quad * 8];
      size_t dg = (size_t)(d0 >> 4) + f1, kb = (size_t)(s0 >> 5) + f0;
      *(s16x8*)(Vf + (size_t)b * BATCH_ELEMS + (dg * 64 + kb) * 512 + lane * 8) = val;
    }
  }
}

// ---------------------------------------------------------------------------
// Flash attention: 16-row blocks, 4 waves quarter D (QK^T from K-in-regs,
// exchange-summed) and quarter cols (PV, V in regs). LDS: exchange + P only.
// MFMA 16x16x32 layouts: A[m=l15][k=quad*8+j], B[k=quad*8+j][n=l15],
// C/D: col=l15, row=quad*4+reg.
// ---------------------------------------------------------------------------
__global__ __launch_bounds__(256, 3)
void attn_kernel(const unsigned short* __restrict__ Kf,
                 const unsigned short* __restrict__ Vf,
                 float* __restrict__ out) {
  __shared__ float Xc[2][4][512];         // parity-dbuf per-wave partial S
  __shared__ unsigned short Pw[4][16 * 40];

  const int bid = blockIdx.x;
  const int bat = bid & 7;                // batch == XCD under round-robin
  const int rg = 127 - (bid >> 3);        // smooth + LPT (heaviest first)
  const int q0 = rg * 16;
  const int tmax = rg >> 1;               // tiles: tmax+1
  const int tid = threadIdx.x;
  const int w = tid >> 6;                 // 0..3: D-quarter / col-quarter
  const int lane = tid & 63;
  const int l15 = lane & 15, quad = lane >> 4;
  const size_t batOff = (size_t)bat * BATCH_ELEMS;

  // K fragments for this wave's D-quarter (db = w*4..w*4+3, both key halves)
  s16x8 kreg[8];
  auto loadK = [&](int kt) {
    const unsigned short* kb = Kf + batOff + (size_t)kt * 16384 + lane * 8;
    #pragma unroll
    for (int i = 0; i < 4; ++i) {
      kreg[i]     = *(const s16x8*)(kb + (size_t)(w * 4 + i) * 512);        // keys 0-15
      kreg[4 + i] = *(const s16x8*)(kb + (size_t)(16 + w * 4 + i) * 512);   // keys 16-31
    }
  };

  // V fragments for this wave's col-quarter (cols w*128..+127), in registers
  s16x8 vreg[8];
  auto loadV = [&](int kt) {
    const unsigned short* vb = Vf + batOff + (size_t)kt * 512 + lane * 8;
    #pragma unroll
    for (int dgl = 0; dgl < 8; ++dgl)
      vreg[dgl] = *(const s16x8*)(vb + (size_t)(w * 8 + dgl) * 32768);
  };

  // prologue: K(0), V(0), Q fragments (latency exposed once)
  loadK(0);
  loadV(0);

  // Q fragments: rows q0..q0+15, D-quarter w (db = w*4 + i)
  s16x8 qf[4];
  {
    const unsigned short* qb =
        Kf + batOff + ((size_t)rg * 16 + w * 4) * 512 + lane * 8;
    #pragma unroll
    for (int i = 0; i < 4; ++i) qf[i] = *(const s16x8*)(qb + i * 512);
  }

  f32x4 O[8];
  float m[4], l[4];
  #pragma unroll
  for (int n = 0; n < 8; ++n) O[n] = (f32x4){0.f, 0.f, 0.f, 0.f};
  #pragma unroll
  for (int r = 0; r < 4; ++r) { m[r] = -3e38f; l[r] = 0.f; }

  for (int kt = 0;; ++kt) {
    const int p = kt & 1;

    // ---- QK^T partial over this wave's D-quarter (K from regs) ----
    f32x4 sacc[2];
    sacc[0] = (f32x4){0.f, 0.f, 0.f, 0.f};
    sacc[1] = (f32x4){0.f, 0.f, 0.f, 0.f};
    __builtin_amdgcn_s_setprio(1);
    #pragma unroll
    for (int i = 0; i < 4; ++i) {
      sacc[0] = __builtin_amdgcn_mfma_f32_16x16x32_bf16(qf[i], kreg[i], sacc[0], 0, 0, 0);
      sacc[1] = __builtin_amdgcn_mfma_f32_16x16x32_bf16(qf[i], kreg[4 + i], sacc[1], 0, 0, 0);
    }
    __builtin_amdgcn_s_setprio(0);

    // ---- prefetch K(t+1) into kreg (WAR pins after QK); lands during
    //      exchange+softmax+PV, consumed next tile (~1200cy later) ----
    if (kt < tmax) loadK(kt + 1);

    // ---- 4-way exchange: publish partial, ONE barrier, fixed-order sum.
    //      Own slot read from regs (same value+order -> bit-identical S). ----
    *(f32x4*)&Xc[p][w][lane * 4] = sacc[0];
    *(f32x4*)&Xc[p][w][256 + lane * 4] = sacc[1];
    asm volatile("s_waitcnt lgkmcnt(0)" ::: "memory");
    __builtin_amdgcn_s_barrier();
    __builtin_amdgcn_sched_barrier(0);
    {
      f32x4 s0 = (f32x4){0.f, 0.f, 0.f, 0.f};
      f32x4 s1 = (f32x4){0.f, 0.f, 0.f, 0.f};
      #pragma unroll
      for (int ww = 0; ww < 4; ++ww) {
        if (ww == w) {
          s0 += sacc[0];
          s1 += sacc[1];
        } else {
          s0 += *(const f32x4*)&Xc[p][ww][lane * 4];
          s1 += *(const f32x4*)&Xc[p][ww][256 + lane * 4];
        }
      }
      sacc[0] = s0;
      sacc[1] = s1;
    }

    if (kt == tmax) {  // causal mask on diagonal tile
      #pragma unroll
      for (int kg2 = 0; kg2 < 2; ++kg2)
        #pragma unroll
        for (int r = 0; r < 4; ++r) {
          int key = kt * 32 + kg2 * 16 + l15;
          int row = q0 + quad * 4 + r;
          if (key > row) sacc[kg2][r] = -3e38f;
        }
    }

    // ---- online softmax (registers + DPP; identical in all 4 waves) ----
    // T13 defer-max: keep sticky m unless tile max exceeds it by >8.
    // Exact: l and p use the same m; p <= e^8 fits fp32/bf16 comfortably.
    float mt[4], alpha[4];
    #pragma unroll
    for (int r = 0; r < 4; ++r)
      mt[r] = red16_max(fmaxf(sacc[0][r], sacc[1][r]));
    bool needAny = (mt[0] > m[0] + 8.f) | (mt[1] > m[1] + 8.f) |
                   (mt[2] > m[2] + 8.f) | (mt[3] > m[3] + 8.f);
    unsigned long long bal = __ballot(needAny);
    if (bal) {
      #pragma unroll
      for (int r = 0; r < 4; ++r) {
        float mn = fmaxf(m[r], mt[r]);
        alpha[r] = __expf(m[r] - mn);
        m[r] = mn;
      }
    } else {
      #pragma unroll
      for (int r = 0; r < 4; ++r) alpha[r] = 1.0f;
    }
    float p2[2][4];
    #pragma unroll
    for (int kg2 = 0; kg2 < 2; ++kg2)
      #pragma unroll
      for (int r = 0; r < 4; ++r) p2[kg2][r] = __expf(sacc[kg2][r] - m[r]);
    #pragma unroll
    for (int r = 0; r < 4; ++r)
      l[r] = l[r] * alpha[r] + red16_sum(p2[0][r] + p2[1][r]);

    // ---- P: C-layout -> A-layout via wave-private LDS ----
    #pragma unroll
    for (int kg2 = 0; kg2 < 2; ++kg2)
      #pragma unroll
      for (int r = 0; r < 4; ++r)
        Pw[w][(quad * 4 + r) * 40 + kg2 * 16 + l15] = f2b_fast(p2[kg2][r]);
    s16x8 pa = *(const s16x8*)&Pw[w][l15 * 40 + quad * 8];

    if (bal) {
      #pragma unroll
      for (int n = 0; n < 8; ++n)
        #pragma unroll
        for (int r = 0; r < 4; ++r) O[n][r] *= alpha[r];
    }

    // ---- PV: O[16 rows][cols w*128..+127] += P(16x32) * V-quarter (regs) ----
    __builtin_amdgcn_s_setprio(1);
    #pragma unroll
    for (int dgl = 0; dgl < 8; ++dgl)
      O[dgl] = __builtin_amdgcn_mfma_f32_16x16x32_bf16(pa, vreg[dgl], O[dgl], 0, 0, 0);
    __builtin_amdgcn_s_setprio(0);

    if (kt == tmax) break;

    // ---- prefetch V(t+1) (WAR pins after PV); no loop-end barrier needed:
    //      Xc parity gives 2-tile reuse distance, barrier(t+1) orders it ----
    loadV(kt + 1);
  }

  // ---- epilogue: wave writes its 16 rows x 128-col quarter ----
  float invl[4];
  #pragma unroll
  for (int r = 0; r < 4; ++r) invl[r] = 1.0f / l[r];
  float* ob = out + ((size_t)(bat * S_LEN + q0)) * D_DIM + w * 128;
  #pragma unroll
  for (int dgl = 0; dgl < 8; ++dgl)
    #pragma unroll
    for (int r = 0; r < 4; ++r)
      ob[(size_t)(quad * 4 + r) * D_DIM + dgl * 16 + l15] = O[dgl][r] * invl[r];
}

extern "C" void kernel_launch(void* const* d_in, const int* in_sizes, int n_in,
                              void* d_out, int out_size, void* d_ws, size_t ws_size,
                              hipStream_t stream) {
  (void)in_sizes; (void)n_in; (void)out_size; (void)ws_size;
  const float* x = (const float*)d_in[0];
  float* out = (float*)d_out;
  unsigned short* Kf = (unsigned short*)d_ws;                         // 16 MiB
  unsigned short* Vf = (unsigned short*)((char*)d_ws + (16u << 20));  // 16 MiB
  pack_kernel<<<2048, 256, 0, stream>>>(x, Kf, Vf);
  attn_kernel<<<1024, 256, 0, stream>>>(Kf, Vf, out);
}